// Round 6
// baseline (374.929 us; speedup 1.0000x reference)
//
#include <hip/hip_runtime.h>

// ---------------------------------------------------------------------------
// DisentangleMultiHeadedAttention on MI355X (gfx950), bf16 MFMA pipeline v6.
// B=4, S=1024, HID=1024, HEADS=16, DH=64.  N_TOK=4096.
// corr_a = qa (ka+kb)^T * scale ; corr_b = qb (ka+kb)^T * scale
//   => one fused ks = k_a@Wa1^T + k_b@Wb1^T (K=2048 GEMM).
// v6: attention processes BOTH streams per block (K staged once, barriers
//     amortized 2x, grid 512 = exactly 2 blocks/CU, single residency round);
//     GEMM at 4 blocks/CU (launch_bounds 256,4).
// ---------------------------------------------------------------------------

typedef __bf16 bf16;
typedef __bf16 bf16x4 __attribute__((ext_vector_type(4)));
typedef __bf16 bf16x8 __attribute__((ext_vector_type(8)));
typedef float  f32x4  __attribute__((ext_vector_type(4)));

#define HID_C   1024
#define S_C     1024
#define B_C     4
#define H_C     16
#define DH_C    64
#define NTOK    4096

__device__ __forceinline__ void gl_lds16(const bf16* g, bf16* l) {
    __builtin_amdgcn_global_load_lds(
        (const __attribute__((address_space(1))) void*)g,
        (__attribute__((address_space(3))) void*)l, 16, 0, 0);
}

// ---------------------------------------------------------------- convert ---
struct CvtArgs {
    const float* src[10];
    bf16*        dst[10];
    int          cum[11];   // cumulative block counts (1024 elems per block)
};

__global__ __launch_bounds__(256) void cvt_all(CvtArgs a) {
    int blk = blockIdx.x;
    int seg = 0;
    while (blk >= a.cum[seg + 1]) ++seg;
    int i = ((blk - a.cum[seg]) * 256 + threadIdx.x) * 4;
    f32x4 v = *(const f32x4*)(a.src[seg] + i);
    *(bf16x4*)(a.dst[seg] + i) = __builtin_convertvector(v, bf16x4);
}

// ------------------------------------------------------------------- GEMM ---
// C[m,n] = (sum_k A[m,k]*W[n,k] (+2nd pair) + bias) * scale
// 128x128 tile, BK=64, global_load_lds(16B), XOR-swizzled LDS chunks
// (conflict-free b128 frag reads).
// Grid (row=32 fastest, col=8, job): id%8 = row%8 -> the 8 col-blocks that
// share one A-strip land on one XCD -> A-strip fetched once [r4: 202->99 MB].
// 4 blocks/CU (LDS 32KB, VGPR<=128) to absorb barrier drains.
// mode 0: bf16 out [B,H,S,DH] | mode 1: bf16 out [B,H,DH,S] | mode 2: f32 out.
struct GemmJob {
    const bf16* A1; const bf16* W1;
    const bf16* A2; const bf16* W2;
    const float* bias1; const float* bias2;
    void* out; int mode; float scale;
};
struct GemmBatch { GemmJob j[5]; };

__global__ __launch_bounds__(256, 4)
void gemm_bt(GemmBatch gb) {
    const GemmJob jb = gb.j[blockIdx.z];
    const int K = HID_C;
    __shared__ bf16 a_lds[128 * 64];
    __shared__ bf16 w_lds[128 * 64];

    const int tid  = threadIdx.x;
    const int wave = tid >> 6, lane = tid & 63;
    const int quad = lane >> 4, l15 = lane & 15;
    const int swz  = l15 & 7;
    const int row0 = blockIdx.x * 128;   // row fastest -> XCD pin per strip
    const int col0 = blockIdx.y * 128;
    const int wr = (wave >> 1) * 64;
    const int wc = (wave & 1) * 64;

    f32x4 acc[4][4] = {};

    const int nkb = jb.A2 ? 32 : 16;
    for (int kb = 0; kb < nkb; ++kb) {
        const bf16* A = (kb < 16) ? jb.A1 : jb.A2;
        const bf16* W = (kb < 16) ? jb.W1 : jb.W2;
        const int k0 = (kb & 15) * 64;
        __syncthreads();
        for (int i = 0; i < 4; ++i) {
            int q = tid + i * 256;
            int r = q >> 3, c = q & 7;
            int gch = c ^ (r & 7);
            gl_lds16(A + (size_t)(row0 + r) * K + k0 + gch * 8, a_lds + q * 8);
            gl_lds16(W + (size_t)(col0 + r) * K + k0 + gch * 8, w_lds + q * 8);
        }
        __syncthreads();
        for (int kk = 0; kk < 2; ++kk) {
            const int ch = ((kk * 4 + quad) ^ swz) * 8;
            bf16x8 af[4], bw[4];
            for (int mi = 0; mi < 4; ++mi)
                af[mi] = *(const bf16x8*)(a_lds + (wr + mi * 16 + l15) * 64 + ch);
            for (int ni = 0; ni < 4; ++ni)
                bw[ni] = *(const bf16x8*)(w_lds + (wc + ni * 16 + l15) * 64 + ch);
            for (int mi = 0; mi < 4; ++mi)
                for (int ni = 0; ni < 4; ++ni)
                    acc[mi][ni] = __builtin_amdgcn_mfma_f32_16x16x32_bf16(af[mi], bw[ni], acc[mi][ni], 0, 0, 0);
        }
    }

    // epilogue.  C layout per 16x16 tile: col(n) = lane&15, row(m) = quad*4+reg.
    for (int mi = 0; mi < 4; ++mi) {
        for (int ni = 0; ni < 4; ++ni) {
            int colg = col0 + wc + ni * 16 + l15;
            float bv = jb.bias1 ? jb.bias1[colg] : 0.f;
            if (jb.bias2) bv += jb.bias2[colg];
            for (int r = 0; r < 4; ++r) {
                int rowg = row0 + wr + mi * 16 + quad * 4 + r;
                float v = (acc[mi][ni][r] + bv) * jb.scale;
                if (jb.mode == 2) {
                    ((float*)jb.out)[(size_t)rowg * HID_C + colg] = v;
                } else {
                    int b = rowg >> 10, s = rowg & 1023;
                    int h = colg >> 6,  d = colg & 63;
                    size_t idx = (jb.mode == 0)
                        ? ((size_t)((b * H_C + h) * S_C + s) * DH_C + d)
                        : ((size_t)((b * H_C + h) * DH_C + d) * S_C + s);
                    ((bf16*)jb.out)[idx] = (bf16)v;
                }
            }
        }
    }
}

// -------------------------------------------------------------- attention ---
// S^T formulation: S^T = K Q^T (A=K, B=Q), O^T = V^T P^T (A=V^T, B=P^T).
// Q pre-scaled by 1/sqrt(2*DH)*log2(e) in its projection; exp2 softmax.
// One block = 128 q-rows x one (b,h) x BOTH streams (K staged once, used by
// both).  4 waves x 32 rows.  Per K-tile: issue V_a/V_b + K(kt+1) async ->
// S^T+softmax both streams (P packed to regs) -> mid-barrier (V drained
// after a full S-phase in flight) -> PV both streams -> end-barrier.
// Grid (bh=64, q=8) = 512 blocks = exactly 2/CU, one residency round;
// id%8 = bh%8 pins each bh's K/V consumers to one XCD L2.
__global__ __launch_bounds__(256, 2)
void attn_fused(const bf16* __restrict__ qp_a, const bf16* __restrict__ qp_b,
                const bf16* __restrict__ ksp,
                const bf16* __restrict__ vT_a, const bf16* __restrict__ vT_b,
                const int* __restrict__ mask,
                bf16* __restrict__ ho_a, bf16* __restrict__ ho_b) {
    __shared__ bf16  k_lds[2][128 * 64];   // [key][d], XOR-swizzled, dbuf
    __shared__ bf16  v_lds[2][64 * 128];   // [stream][d][key], single-buffered
    __shared__ float madd[1024];           // 0 or -1e9 per key
    __shared__ bf16  p_lds[4 * 32 * 40];   // per-wave [qrow][key32] pad->40

    const int tid  = threadIdx.x;
    const int wave = tid >> 6, lane = tid & 63;
    const int quad = lane >> 4, l15 = lane & 15;
    const int swz  = l15 & 7;
    const int bh = blockIdx.x;             // XCD-locality: bh fastest
    const int b  = bh >> 4, h = bh & 15;
    const int s0 = blockIdx.y * 128;

    const bf16* qs[2] = {qp_a, qp_b};
    const bf16* vs[2] = {vT_a, vT_b};
    bf16*       hs[2] = {ho_a, ho_b};

    // mask -> additive table
    {
        int4 mv = *(const int4*)(mask + b * S_C + tid * 4);
        f32x4 md;
        md[0] = mv.x ? 0.f : -1e9f;
        md[1] = mv.y ? 0.f : -1e9f;
        md[2] = mv.z ? 0.f : -1e9f;
        md[3] = mv.w ? 0.f : -1e9f;
        *(f32x4*)(madd + tid * 4) = md;
    }

    // Q B-fragments, both streams, live in registers all kernel (pre-scaled)
    bf16x8 qf[2][2][2];                    // [st][qt][kk]
    for (int st = 0; st < 2; ++st)
        for (int qt = 0; qt < 2; ++qt)
            for (int kk = 0; kk < 2; ++kk)
                qf[st][qt][kk] = *(const bf16x8*)(qs[st]
                    + ((size_t)bh * S_C + s0 + wave * 32 + qt * 16 + l15) * DH_C
                    + kk * 32 + quad * 8);

    const bf16* kbase0 = ksp + (size_t)bh * S_C * DH_C;

    float m_i[2][2], l_i[2][2];
    for (int st = 0; st < 2; ++st)
        for (int qt = 0; qt < 2; ++qt) { m_i[st][qt] = -1e30f; l_i[st][qt] = 0.f; }
    f32x4  Oacc[2][2][4] = {};             // [st][qt][dt]  O^T[d][qrow]
    bf16x4 pk[2][8][2];                    // [st][ct][qt]  packed P (4 keys)
    bf16* pw = p_lds + wave * (32 * 40);

    // prime K[0]
    for (int i = 0; i < 4; ++i) {
        int q = tid + i * 256;
        int r = q >> 3, c = q & 7;
        gl_lds16(kbase0 + r * DH_C + ((c ^ (r & 7)) * 8), &k_lds[0][q * 8]);
    }
    __syncthreads();

    for (int kt = 0; kt < 8; ++kt) {
        const int cur = kt & 1;
        // issue V for both streams (consumed after mid-barrier)
        for (int st = 0; st < 2; ++st) {
            const bf16* vb = vs[st] + (size_t)bh * DH_C * S_C + kt * 128;
            for (int i = 0; i < 4; ++i) {
                int q = tid + i * 256;
                int d = q >> 4, c16 = q & 15;
                gl_lds16(vb + (size_t)d * S_C + ((c16 ^ (d & 7)) * 8), &v_lds[st][q * 8]);
            }
        }
        // issue K prefetch (consumed next iteration)
        if (kt < 7) {
            const bf16* kb = kbase0 + (kt + 1) * 128 * DH_C;
            for (int i = 0; i < 4; ++i) {
                int q = tid + i * 256;
                int r = q >> 3, c = q & 7;
                gl_lds16(kb + r * DH_C + ((c ^ (r & 7)) * 8), &k_lds[1 - cur][q * 8]);
            }
        }
        const bf16* kl = k_lds[cur];

        // --- S^T + softmax + pack, per stream (sacc reused) ---
        for (int st = 0; st < 2; ++st) {
            f32x4 sacc[8][2] = {};
            for (int kk = 0; kk < 2; ++kk) {
                const int ch = ((kk * 4 + quad) ^ swz) * 8;
                for (int ct = 0; ct < 8; ++ct) {
                    bf16x8 kf = *(const bf16x8*)(kl + (ct * 16 + l15) * 64 + ch);
                    sacc[ct][0] = __builtin_amdgcn_mfma_f32_16x16x32_bf16(kf, qf[st][0][kk], sacc[ct][0], 0, 0, 0);
                    sacc[ct][1] = __builtin_amdgcn_mfma_f32_16x16x32_bf16(kf, qf[st][1][kk], sacc[ct][1], 0, 0, 0);
                }
            }
            for (int ct = 0; ct < 8; ++ct) {
                f32x4 md = *(const f32x4*)(madd + kt * 128 + ct * 16 + quad * 4);
                for (int qt = 0; qt < 2; ++qt)
                    for (int r = 0; r < 4; ++r)
                        sacc[ct][qt][r] += md[r];
            }
            for (int qt = 0; qt < 2; ++qt) {
                float tm = sacc[0][qt][0];
                for (int ct = 0; ct < 8; ++ct)
                    for (int r = 0; r < 4; ++r) tm = fmaxf(tm, sacc[ct][qt][r]);
                tm = fmaxf(tm, __shfl_xor(tm, 16, 64));
                tm = fmaxf(tm, __shfl_xor(tm, 32, 64));
                float mn = fmaxf(m_i[st][qt], tm);
                float fac = __builtin_amdgcn_exp2f(m_i[st][qt] - mn);
                m_i[st][qt] = mn;
                float ts = 0.f;
                for (int ct = 0; ct < 8; ++ct)
                    for (int r = 0; r < 4; ++r) {
                        float p = __builtin_amdgcn_exp2f(sacc[ct][qt][r] - mn);
                        sacc[ct][qt][r] = p;
                        ts += p;
                    }
                ts += __shfl_xor(ts, 16, 64);
                ts += __shfl_xor(ts, 32, 64);
                l_i[st][qt] = l_i[st][qt] * fac + ts;
                for (int dt = 0; dt < 4; ++dt)
                    for (int r = 0; r < 4; ++r) Oacc[st][qt][dt][r] *= fac;
                for (int ct = 0; ct < 8; ++ct)
                    pk[st][ct][qt] = __builtin_convertvector(sacc[ct][qt], bf16x4);
            }
        }

        __syncthreads();   // V_a/V_b drained (issued a full S-phase ago)

        // --- PV per stream: chunk-wise P relayout (wave-private LDS) ---
        for (int st = 0; st < 2; ++st) {
            const bf16* vl = v_lds[st];
            for (int c = 0; c < 4; ++c) {
                for (int qt = 0; qt < 2; ++qt)
                    for (int half = 0; half < 2; ++half)
                        *(bf16x4*)(pw + (qt * 16 + l15) * 40 + half * 16 + quad * 4)
                            = pk[st][2 * c + half][qt];
                bf16x8 pf0 = *(const bf16x8*)(pw + l15 * 40 + quad * 8);
                bf16x8 pf1 = *(const bf16x8*)(pw + (16 + l15) * 40 + quad * 8);
                for (int dt = 0; dt < 4; ++dt) {
                    bf16x8 vf = *(const bf16x8*)(vl + (dt * 16 + l15) * 128 + ((c * 4 + quad) ^ swz) * 8);
                    Oacc[st][0][dt] = __builtin_amdgcn_mfma_f32_16x16x32_bf16(vf, pf0, Oacc[st][0][dt], 0, 0, 0);
                    Oacc[st][1][dt] = __builtin_amdgcn_mfma_f32_16x16x32_bf16(vf, pf1, Oacc[st][1][dt], 0, 0, 0);
                }
            }
        }

        __syncthreads();   // v_lds / p_lds free for next iteration
    }

    // epilogue: O^T frag col(n)=l15=qrow, row(m)=quad*4+r=d -> pack 4 features
    for (int st = 0; st < 2; ++st)
        for (int qt = 0; qt < 2; ++qt) {
            float inv = 1.f / l_i[st][qt];
            int token = s0 + wave * 32 + qt * 16 + l15;
            for (int dt = 0; dt < 4; ++dt) {
                f32x4 o;
                for (int r = 0; r < 4; ++r) o[r] = Oacc[st][qt][dt][r] * inv;
                bf16x4 ob = __builtin_convertvector(o, bf16x4);
                *(bf16x4*)(hs[st] + (size_t)(b * S_C + token) * HID_C + h * DH_C + dt * 16 + quad * 4) = ob;
            }
        }
}

// ----------------------------------------------------------------- launch ---
extern "C" void kernel_launch(void* const* d_in, const int* in_sizes, int n_in,
                              void* d_out, int out_size, void* d_ws, size_t ws_size,
                              hipStream_t stream) {
    const float* q_a  = (const float*)d_in[0];
    const float* k_a  = (const float*)d_in[1];
    const float* v_a  = (const float*)d_in[2];
    const float* q_b  = (const float*)d_in[3];
    const float* k_b  = (const float*)d_in[4];
    const float* v_b  = (const float*)d_in[5];
    const int*   mask = (const int*)  d_in[6];
    const float* Wa   = (const float*)d_in[7];
    const float* ba   = (const float*)d_in[8];
    const float* Wb   = (const float*)d_in[9];
    const float* bb   = (const float*)d_in[10];
    const float* Wo_a = (const float*)d_in[11];
    const float* bo_a = (const float*)d_in[12];
    const float* Wo_b = (const float*)d_in[13];
    const float* bo_b = (const float*)d_in[14];
    float* out = (float*)d_out;

    constexpr size_t ACT = (size_t)NTOK * HID_C;       // 4,194,304
    constexpr size_t W3  = 3 * (size_t)HID_C * HID_C;  // 3,145,728
    constexpr size_t W1  = (size_t)HID_C * HID_C;      // 1,048,576
    // softmax scale * log2(e), folded into Q projections
    const float SC2 = 0.08838834764831845f * 1.4426950408889634f;

    bf16* w = (bf16*)d_ws;
    bf16* bfa[6];
    for (int i = 0; i < 6; ++i) bfa[i] = w + (size_t)i * ACT;
    bf16* bfWa  = w + 6 * ACT;
    bf16* bfWb  = bfWa + W3;
    bf16* bfWoA = bfWb + W3;
    bf16* bfWoB = bfWoA + W1;
    bf16* qa_p  = bfWoB + W1;
    bf16* qb_p  = qa_p + ACT;
    bf16* ks_p  = qb_p + ACT;
    bf16* vTa   = ks_p + ACT;
    bf16* vTb   = vTa + ACT;
    bf16* ha    = vTb + ACT;
    bf16* hb    = ha + ACT;

    // 1) all fp32->bf16 converts in ONE launch (activations + weights)
    CvtArgs ca;
    const float* srcs[10] = {q_a, k_a, v_a, q_b, k_b, v_b, Wa, Wb, Wo_a, Wo_b};
    bf16* dsts[10] = {bfa[0], bfa[1], bfa[2], bfa[3], bfa[4], bfa[5], bfWa, bfWb, bfWoA, bfWoB};
    int nblk[10] = {4096, 4096, 4096, 4096, 4096, 4096, 3072, 3072, 1024, 1024};
    int cum = 0;
    for (int i = 0; i < 10; ++i) { ca.src[i] = srcs[i]; ca.dst[i] = dsts[i]; ca.cum[i] = cum; cum += nblk[i]; }
    ca.cum[10] = cum;
    cvt_all<<<cum, 256, 0, stream>>>(ca);

    // 2) all 5 projections in ONE launch (z=job, ks first: 2x-K job's blocks
    //    dispatch earliest so its tail overlaps the others)
    GemmBatch g1;
    g1.j[0] = { bfa[1], bfWa + W1,     bfa[4], bfWb + W1, ba + 1024, bb + 1024, ks_p, 0, 1.f  };
    g1.j[1] = { bfa[0], bfWa,          nullptr, nullptr,  ba,        nullptr,   qa_p, 0, SC2 };
    g1.j[2] = { bfa[3], bfWb,          nullptr, nullptr,  bb,        nullptr,   qb_p, 0, SC2 };
    g1.j[3] = { bfa[2], bfWa + 2 * W1, nullptr, nullptr,  ba + 2048, nullptr,   vTa,  1, 1.f  };
    g1.j[4] = { bfa[5], bfWb + 2 * W1, nullptr, nullptr,  bb + 2048, nullptr,   vTb,  1, 1.f  };
    gemm_bt<<<dim3(NTOK / 128, HID_C / 128, 5), 256, 0, stream>>>(g1);

    // 3) fused attention, both streams per block, XCD-locality grid
    dim3 ga(B_C * H_C, S_C / 128);     // (64, 8) = 512 blocks = 2/CU exact
    attn_fused<<<ga, 256, 0, stream>>>(qa_p, qb_p, ks_p, vTa, vTb, mask, ha, hb);

    // 4) both output projections in ONE launch -> fp32 d_out
    GemmBatch g2;
    g2.j[0] = { ha, bfWoA, nullptr, nullptr, bo_a, nullptr, (void*)out, 2, 1.f };
    g2.j[1] = { hb, bfWoB, nullptr, nullptr, bo_b, nullptr,
                (void*)(out + (size_t)NTOK * HID_C), 2, 1.f };
    g2.j[2] = g2.j[0]; g2.j[3] = g2.j[0]; g2.j[4] = g2.j[0];  // unused
    gemm_bt<<<dim3(NTOK / 128, HID_C / 128, 2), 256, 0, stream>>>(g2);
}